// Round 1
// baseline (289.372 us; speedup 1.0000x reference)
//
#include <hip/hip_runtime.h>

// Chunked linear attention (causal, unnormalized), bf16 MFMA, fp32 I/O.
// R4: split-scan phA.
//   phA: grid (bh, dv-slice16, seg): each block scans only CPS=4 chunks,
//        storing local exclusive prefixes in slots 4s+j (j>0) and the
//        segment TOTAL T_s in slot 4s (previously an all-zero matrix).
//        4x shorter serial chain, 2048 blocks (4/CU by LDS) vs 512.
//   phB: per (bh, n=4s+j): H_n = sum_{sig<s} T_sig + local(n), summed in
//        fp32 during H staging; rest unchanged. bh colocated per XCD so
//        carry totals hit L2.
// B=4 S=2048 H=16 D=128. ws: 64*16*128*128 bf16 = 32 MiB.

#define Bc 4
#define Sq 2048
#define Hh 16
#define Dd 128
#define RS (Hh * Dd)      // 2048
#define Cc 128
#define NCH (Sq / Cc)     // 16
#define BHt (Bc * Hh)     // 64
#define NSEG 4
#define CPS (NCH / NSEG)  // 4
#define SCALE 0.08838834764831845f

using frag_ab = __attribute__((ext_vector_type(8))) short;  // 8 bf16
using frag_cd = __attribute__((ext_vector_type(4))) float;  // 4 fp32

__device__ __forceinline__ unsigned short f2bf(float f) {
  union { float f; unsigned u; } x; x.f = f;
  unsigned r = x.u + 0x7FFFu + ((x.u >> 16) & 1u);  // RNE
  return (unsigned short)(r >> 16);
}
__device__ __forceinline__ float bf2f(unsigned short u) {
  union { unsigned u; float f; } x; x.u = ((unsigned)u) << 16;
  return x.f;
}
// swizzles: permute 8-element (16 B) blocks within a row -> frag b128 reads
// stay contiguous; writes spread across banks.
__device__ __forceinline__ int sw64(int r, int c) {
  return r * 64 + ((((c >> 3) ^ (r & 7)) << 3) | (c & 7));
}
__device__ __forceinline__ int sw128(int r, int c) {
  return r * 128 + ((((c >> 3) ^ (r & 15)) << 3) | (c & 7));
}
__device__ __forceinline__ int swKT(int dk, int t) {  // [dk 128][t 128]
  return dk * 128 + ((((t >> 3) ^ (dk ^ (dk >> 4))) & 15) << 3) + (t & 7);
}
__device__ __forceinline__ int swVT(int dv, int t) {  // [dv 16][t 128]
  return dv * 128 + ((((t >> 3) ^ dv) & 15) << 3) + (t & 7);
}

// ---------- phA: split scan. Block = (bh, slice, seg); scans CPS chunks ----
// bid layout: bh in low 6 bits (slices+segs of one bh share an XCD -> L2
// absorbs the 8x redundant K read), slice bits 6-8, seg bits 9+.
__global__ __launch_bounds__(256) void phA_state(const float* __restrict__ kg,
                                                 const float* __restrict__ vg,
                                                 unsigned short* __restrict__ st) {
  __shared__ unsigned short KT[128 * 128];  // 32 KB [dk][t]
  __shared__ unsigned short VT[16 * 128];   //  4 KB [dv][t]
  const int tid = threadIdx.x;
  const int bh = blockIdx.x & 63;
  const int slice = (blockIdx.x >> 6) & 7;
  const int seg = blockIdx.x >> 9;
  const int b = bh >> 4, h = bh & 15;
  const int dv0 = slice * 16;
  const size_t base = (size_t)b * Sq * RS + (size_t)h * Dd;
  const int w = tid >> 6, L = tid & 63, li = L & 15, q4 = L >> 4;
  // K staging: thread owns a 4t x 4dk micro-tile per pass (gather transpose)
  const int kdk0 = (tid & 31) * 4;
  const int ktg4 = (tid >> 5) * 4;      // t sub-offset 0..28
  // V staging: thread owns 2t x 4dv
  const int vdv0l = (tid & 3) * 4;
  const int vt0 = (tid >> 2) * 2;       // 0..126

  float4 rk[4][4];
  float4 rv[2];
  auto prefetch = [&](int n) {
    const size_t t0g = (size_t)n * Cc;
#pragma unroll
    for (int p = 0; p < 4; ++p) {
      const int t0 = p * 32 + ktg4;
#pragma unroll
      for (int i = 0; i < 4; ++i)
        rk[p][i] = *(const float4*)(kg + base + (t0g + t0 + i) * (size_t)RS + kdk0);
    }
#pragma unroll
    for (int i = 0; i < 2; ++i)
      rv[i] = *(const float4*)(vg + base + (t0g + vt0 + i) * (size_t)RS + dv0 + vdv0l);
  };

  frag_cd acc[2];
  acc[0] = (frag_cd){0.f, 0.f, 0.f, 0.f};
  acc[1] = (frag_cd){0.f, 0.f, 0.f, 0.f};
  const int n0 = seg * CPS;
  prefetch(n0);
  const size_t sbb = (size_t)bh * NCH * (128 * 128);

  auto store_acc = [&](int slot) {
    const size_t sb = sbb + (size_t)slot * (128 * 128);
#pragma unroll
    for (int nt = 0; nt < 2; ++nt)
#pragma unroll
      for (int r = 0; r < 4; ++r) {
        const int dv = dv0 + 4 * q4 + r;
        const int dk = 32 * w + 16 * nt + li;
        st[sb + (size_t)dv * 128 + dk] = f2bf(acc[nt][r]);
      }
  };

  for (int j = 0; j < CPS; ++j) {
    __syncthreads();  // prev chunk's frag reads done
    // stage K^T (ushort4 along t) and V^T (ushort2 along t)
#pragma unroll
    for (int p = 0; p < 4; ++p) {
      const int t0 = p * 32 + ktg4;
#pragma unroll
      for (int jj = 0; jj < 4; ++jj) {
        ushort4 u;
        u.x = f2bf(((const float*)&rk[p][0])[jj]);
        u.y = f2bf(((const float*)&rk[p][1])[jj]);
        u.z = f2bf(((const float*)&rk[p][2])[jj]);
        u.w = f2bf(((const float*)&rk[p][3])[jj]);
        *(ushort4*)&KT[swKT(kdk0 + jj, t0)] = u;
      }
    }
#pragma unroll
    for (int jj = 0; jj < 4; ++jj) {
      ushort2 u;
      u.x = f2bf(((const float*)&rv[0])[jj]);
      u.y = f2bf(((const float*)&rv[1])[jj]);
      *(ushort2*)&VT[swVT(vdv0l + jj, vt0)] = u;
    }
    if (j + 1 < CPS) prefetch(n0 + j + 1);  // HBM latency hides under LDS+MFMA
    __syncthreads();
    // store local EXCLUSIVE prefix (slot 4s+j, j>0; j==0 local prefix is 0)
    if (j > 0) store_acc(n0 + j);
    // acc[dv][dk] += V^T K  (wave w owns dk in [32w, 32w+32))
#pragma unroll
    for (int kt = 0; kt < 4; ++kt) {
      frag_ab af = *(const frag_ab*)&VT[swVT(li, 32 * kt + 8 * q4)];
#pragma unroll
      for (int nt = 0; nt < 2; ++nt) {
        frag_ab bf = *(const frag_ab*)&KT[swKT(32 * w + 16 * nt + li, 32 * kt + 8 * q4)];
        acc[nt] = __builtin_amdgcn_mfma_f32_16x16x32_bf16(af, bf, acc[nt], 0, 0, 0);
      }
    }
  }
  // segment total T_seg -> slot n0 (unused by last segment's consumers)
  if (seg + 1 < NSEG) store_acc(n0);
}

// ---------- phB: O = Qs*H_n + tril(Qs*K^T)*V ----------
// H_n = sum_{sig < n>>2} T_sig (slots 4*sig) + local (slot n, if n&3).
// bid: bh in low 6 bits -> a bh's 16 chunks share an XCD (carry totals in L2).
__global__ __launch_bounds__(256) void phB_out(const float* __restrict__ qg,
                                               const float* __restrict__ kg,
                                               const float* __restrict__ vg,
                                               const unsigned short* __restrict__ st,
                                               float* __restrict__ o) {
  __shared__ unsigned short QP[128 * 128];  // 32 KB: Qs, later P
  __shared__ unsigned short Bb[128 * 64];   // 16 KB: H / K / V^T halves
  const int tid = threadIdx.x;
  const int bid = blockIdx.x;
  const int bh = bid & 63, n = bid >> 6;
  const int b = bh >> 4, h = bh & 15;
  const size_t cbase = (size_t)b * Sq * RS + (size_t)n * Cc * RS + (size_t)h * Dd;
  const size_t sbh = (size_t)bh * NCH * (128 * 128);
  const int sseg = n >> 2, jj = n & 3;
  const int nmat = sseg + (jj ? 1 : 0);
  const int w = tid >> 6, L = tid & 63;
  const int wr = w >> 1, wc = w & 1, li = L & 15, q4 = L >> 4;

  // stage Qs full (scaled) -> QP
#pragma unroll
  for (int it = 0; it < 16; ++it) {
    const int f = it * 256 + tid;
    const int t = f >> 5;
    const int c0 = (f & 31) << 2;
    const float4 q4v = *(const float4*)(qg + cbase + (size_t)t * RS + c0);
    ushort4 qu;
    qu.x = f2bf(q4v.x * SCALE); qu.y = f2bf(q4v.y * SCALE);
    qu.z = f2bf(q4v.z * SCALE); qu.w = f2bf(q4v.w * SCALE);
    *(ushort4*)&QP[sw128(t, c0)] = qu;
  }
  frag_cd accO[4][4], accP[4][4];
#pragma unroll
  for (int i = 0; i < 4; ++i)
#pragma unroll
    for (int j = 0; j < 4; ++j) {
      accO[i][j] = (frag_cd){0.f, 0.f, 0.f, 0.f};
      accP[i][j] = (frag_cd){0.f, 0.f, 0.f, 0.f};
    }

  // ---- H-GEMM: accO = Qs (from QP) x H  (H = carry totals + local) ----
  if (nmat > 0) {
    for (int half = 0; half < 2; ++half) {
      __syncthreads();  // half0: QP visible; half1: Bb reads done
      if (nmat == 1) {
        const int slot = sseg ? 0 : n;  // sseg==1,jj==0 -> T_0; else local n
#pragma unroll
        for (int it = 0; it < 4; ++it) {
          const int f = it * 256 + tid;
          const int dv = f >> 3;
          const int c8 = (f & 7) << 3;
          const uint4 hv = *(const uint4*)(st + sbh + ((size_t)slot << 14) +
                                           (size_t)dv * 128 + 64 * half + c8);
          *(uint4*)&Bb[sw64(dv, c8)] = hv;
        }
      } else {
#pragma unroll
        for (int it = 0; it < 4; ++it) {
          const int f = it * 256 + tid;
          const int dv = f >> 3;
          const int c8 = (f & 7) << 3;
          float s8[8];
#pragma unroll
          for (int e = 0; e < 8; ++e) s8[e] = 0.f;
          for (int m = 0; m < nmat; ++m) {
            const int slot = (m < sseg) ? (m << 2) : n;
            const uint4 hv = *(const uint4*)(st + sbh + ((size_t)slot << 14) +
                                             (size_t)dv * 128 + 64 * half + c8);
            const unsigned hw[4] = {hv.x, hv.y, hv.z, hv.w};
#pragma unroll
            for (int e = 0; e < 4; ++e) {
              s8[2 * e + 0] += bf2f((unsigned short)(hw[e] & 0xFFFFu));
              s8[2 * e + 1] += bf2f((unsigned short)(hw[e] >> 16));
            }
          }
          unsigned pk[4];
#pragma unroll
          for (int e = 0; e < 4; ++e)
            pk[e] = (unsigned)f2bf(s8[2 * e]) | ((unsigned)f2bf(s8[2 * e + 1]) << 16);
          uint4 hv; hv.x = pk[0]; hv.y = pk[1]; hv.z = pk[2]; hv.w = pk[3];
          *(uint4*)&Bb[sw64(dv, c8)] = hv;
        }
      }
      __syncthreads();
#pragma unroll
      for (int kt = 0; kt < 2; ++kt) {
        const int ktg = 2 * half + kt;
        frag_ab af[4], bf_[4];
#pragma unroll
        for (int mt = 0; mt < 4; ++mt)
          af[mt] = *(const frag_ab*)&QP[sw128(64 * wr + 16 * mt + li, 32 * ktg + 8 * q4)];
#pragma unroll
        for (int nt = 0; nt < 4; ++nt)
          bf_[nt] = *(const frag_ab*)&Bb[sw64(64 * wc + 16 * nt + li, 32 * kt + 8 * q4)];
#pragma unroll
        for (int mt = 0; mt < 4; ++mt)
#pragma unroll
          for (int nt = 0; nt < 4; ++nt)
            accO[mt][nt] = __builtin_amdgcn_mfma_f32_16x16x32_bf16(af[mt], bf_[nt], accO[mt][nt], 0, 0, 0);
      }
    }
  }

  // ---- GEMM1: accP = Qs x K^T (triangle-skipped) ----
  for (int half = 0; half < 2; ++half) {
    __syncthreads();
#pragma unroll
    for (int it = 0; it < 8; ++it) {
      const int f = it * 256 + tid;
      const int t = f >> 4;
      const int c0 = (f & 15) << 2;
      const float4 k4v = *(const float4*)(kg + cbase + (size_t)t * RS + 64 * half + c0);
      ushort4 ku;
      ku.x = f2bf(k4v.x); ku.y = f2bf(k4v.y); ku.z = f2bf(k4v.z); ku.w = f2bf(k4v.w);
      *(ushort4*)&Bb[sw64(t, c0)] = ku;
    }
    __syncthreads();
    if (64 * wc <= 64 * wr + 63) {
#pragma unroll
      for (int kt = 0; kt < 2; ++kt) {
        const int ktg = 2 * half + kt;
        frag_ab af[4], bf_[4];
#pragma unroll
        for (int mt = 0; mt < 4; ++mt)
          af[mt] = *(const frag_ab*)&QP[sw128(64 * wr + 16 * mt + li, 32 * ktg + 8 * q4)];
#pragma unroll
        for (int nt = 0; nt < 4; ++nt)
          bf_[nt] = *(const frag_ab*)&Bb[sw64(64 * wc + 16 * nt + li, 32 * kt + 8 * q4)];
#pragma unroll
        for (int mt = 0; mt < 4; ++mt)
#pragma unroll
          for (int nt = 0; nt < 4; ++nt)
            if (64 * wc + 16 * nt <= 64 * wr + 16 * mt + 15)
              accP[mt][nt] = __builtin_amdgcn_mfma_f32_16x16x32_bf16(af[mt], bf_[nt], accP[mt][nt], 0, 0, 0);
      }
    }
  }
  __syncthreads();  // all QP (Qs) reads done -> safe to overwrite with P
  // masked P (s<=t) -> QP
#pragma unroll
  for (int mt = 0; mt < 4; ++mt)
#pragma unroll
    for (int nt = 0; nt < 4; ++nt) {
      const int t0 = 64 * wr + 16 * mt + 4 * q4;
      const int s = 64 * wc + 16 * nt + li;
#pragma unroll
      for (int r = 0; r < 4; ++r) {
        const int t = t0 + r;
        QP[sw128(t, s)] = (s <= t) ? f2bf(accP[mt][nt][r]) : (unsigned short)0;
      }
    }

  // ---- GEMM2: accO += P x V  (V^T staged into Bb) ----
  for (int half = 0; half < 2; ++half) {
    __syncthreads();  // P visible / Bb reads done
#pragma unroll
    for (int it = 0; it < 8; ++it) {
      const int sl = (tid & 15) | ((it & 3) << 4);
      const int c0 = ((tid >> 4) | ((it >> 2) << 4)) << 2;
      const int s = 64 * half + sl;
      const float4 v4v = *(const float4*)(vg + cbase + (size_t)s * RS + c0);
      Bb[sw64(c0 + 0, sl)] = f2bf(v4v.x);
      Bb[sw64(c0 + 1, sl)] = f2bf(v4v.y);
      Bb[sw64(c0 + 2, sl)] = f2bf(v4v.z);
      Bb[sw64(c0 + 3, sl)] = f2bf(v4v.w);
    }
    __syncthreads();
#pragma unroll
    for (int kt = 0; kt < 2; ++kt) {
      const int ktg = 2 * half + kt;
      if (32 * ktg > 64 * wr + 63) continue;
      frag_ab af[4], bf_[4];
#pragma unroll
      for (int mt = 0; mt < 4; ++mt)
        af[mt] = *(const frag_ab*)&QP[sw128(64 * wr + 16 * mt + li, 32 * ktg + 8 * q4)];
#pragma unroll
      for (int nt = 0; nt < 4; ++nt)
        bf_[nt] = *(const frag_ab*)&Bb[sw64(64 * wc + 16 * nt + li, 32 * kt + 8 * q4)];
#pragma unroll
      for (int mt = 0; mt < 4; ++mt)
#pragma unroll
        for (int nt = 0; nt < 4; ++nt)
          if (32 * ktg <= 64 * wr + 16 * mt + 15)
            accO[mt][nt] = __builtin_amdgcn_mfma_f32_16x16x32_bf16(af[mt], bf_[nt], accO[mt][nt], 0, 0, 0);
    }
  }
  // store O fp32 (single write, no RMW)
#pragma unroll
  for (int mt = 0; mt < 4; ++mt)
#pragma unroll
    for (int nt = 0; nt < 4; ++nt)
#pragma unroll
      for (int r = 0; r < 4; ++r) {
        const int t = 64 * wr + 16 * mt + 4 * q4 + r;
        const int dv = 64 * wc + 16 * nt + li;
        o[cbase + (size_t)t * RS + dv] = accO[mt][nt][r];
      }
}

extern "C" void kernel_launch(void* const* d_in, const int* in_sizes, int n_in,
                              void* d_out, int out_size, void* d_ws, size_t ws_size,
                              hipStream_t stream) {
  const float* q = (const float*)d_in[0];
  const float* k = (const float*)d_in[1];
  const float* v = (const float*)d_in[2];
  float* o = (float*)d_out;
  unsigned short* st = (unsigned short*)d_ws;  // 32 MiB
  hipLaunchKernelGGL(phA_state, dim3(BHt * 8 * NSEG), dim3(256), 0, stream, k, v, st);
  hipLaunchKernelGGL(phB_out, dim3(BHt * NCH), dim3(256), 0, stream, q, k, v, st, o);
}

// Round 2
// 284.002 us; speedup vs baseline: 1.0189x; 1.0189x over previous
//
#include <hip/hip_runtime.h>

// Chunked linear attention (causal, unnormalized), bf16 MFMA, fp32 I/O.
// R5: t-split phB.
//   phA: unchanged split-scan (grid bh x slice x seg, CPS=4 chunks/block).
//   phB: block = (bh, n, tb): tb selects 64 query rows of the 128-chunk.
//        QP 16 KB + Bb 16 KB = 32 KB LDS -> 5 blocks/CU; acc regs halved.
//        tb=0 skips masked half of GEMM1/GEMM2 (s<=t<64). Grid 2048.
// B=4 S=2048 H=16 D=128. ws: 64*16*128*128 bf16 = 32 MiB.

#define Bc 4
#define Sq 2048
#define Hh 16
#define Dd 128
#define RS (Hh * Dd)      // 2048
#define Cc 128
#define NCH (Sq / Cc)     // 16
#define BHt (Bc * Hh)     // 64
#define NSEG 4
#define CPS (NCH / NSEG)  // 4
#define SCALE 0.08838834764831845f

using frag_ab = __attribute__((ext_vector_type(8))) short;  // 8 bf16
using frag_cd = __attribute__((ext_vector_type(4))) float;  // 4 fp32

__device__ __forceinline__ unsigned short f2bf(float f) {
  union { float f; unsigned u; } x; x.f = f;
  unsigned r = x.u + 0x7FFFu + ((x.u >> 16) & 1u);  // RNE
  return (unsigned short)(r >> 16);
}
__device__ __forceinline__ float bf2f(unsigned short u) {
  union { unsigned u; float f; } x; x.u = ((unsigned)u) << 16;
  return x.f;
}
// swizzles: permute 8-element (16 B) blocks within a row -> frag b128 reads
// stay contiguous; writes spread across banks.
__device__ __forceinline__ int sw64(int r, int c) {
  return r * 64 + ((((c >> 3) ^ (r & 7)) << 3) | (c & 7));
}
__device__ __forceinline__ int sw128(int r, int c) {
  return r * 128 + ((((c >> 3) ^ (r & 15)) << 3) | (c & 7));
}
__device__ __forceinline__ int swKT(int dk, int t) {  // [dk 128][t 128]
  return dk * 128 + ((((t >> 3) ^ (dk ^ (dk >> 4))) & 15) << 3) + (t & 7);
}
__device__ __forceinline__ int swVT(int dv, int t) {  // [dv 16][t 128]
  return dv * 128 + ((((t >> 3) ^ dv) & 15) << 3) + (t & 7);
}

// ---------- phA: split scan. Block = (bh, slice, seg); scans CPS chunks ----
// bid layout: bh in low 6 bits (slices+segs of one bh share an XCD -> L2
// absorbs the 8x redundant K read), slice bits 6-8, seg bits 9+.
__global__ __launch_bounds__(256) void phA_state(const float* __restrict__ kg,
                                                 const float* __restrict__ vg,
                                                 unsigned short* __restrict__ st) {
  __shared__ unsigned short KT[128 * 128];  // 32 KB [dk][t]
  __shared__ unsigned short VT[16 * 128];   //  4 KB [dv][t]
  const int tid = threadIdx.x;
  const int bh = blockIdx.x & 63;
  const int slice = (blockIdx.x >> 6) & 7;
  const int seg = blockIdx.x >> 9;
  const int b = bh >> 4, h = bh & 15;
  const int dv0 = slice * 16;
  const size_t base = (size_t)b * Sq * RS + (size_t)h * Dd;
  const int w = tid >> 6, L = tid & 63, li = L & 15, q4 = L >> 4;
  // K staging: thread owns a 4t x 4dk micro-tile per pass (gather transpose)
  const int kdk0 = (tid & 31) * 4;
  const int ktg4 = (tid >> 5) * 4;      // t sub-offset 0..28
  // V staging: thread owns 2t x 4dv
  const int vdv0l = (tid & 3) * 4;
  const int vt0 = (tid >> 2) * 2;       // 0..126

  float4 rk[4][4];
  float4 rv[2];
  auto prefetch = [&](int n) {
    const size_t t0g = (size_t)n * Cc;
#pragma unroll
    for (int p = 0; p < 4; ++p) {
      const int t0 = p * 32 + ktg4;
#pragma unroll
      for (int i = 0; i < 4; ++i)
        rk[p][i] = *(const float4*)(kg + base + (t0g + t0 + i) * (size_t)RS + kdk0);
    }
#pragma unroll
    for (int i = 0; i < 2; ++i)
      rv[i] = *(const float4*)(vg + base + (t0g + vt0 + i) * (size_t)RS + dv0 + vdv0l);
  };

  frag_cd acc[2];
  acc[0] = (frag_cd){0.f, 0.f, 0.f, 0.f};
  acc[1] = (frag_cd){0.f, 0.f, 0.f, 0.f};
  const int n0 = seg * CPS;
  prefetch(n0);
  const size_t sbb = (size_t)bh * NCH * (128 * 128);

  auto store_acc = [&](int slot) {
    const size_t sb = sbb + (size_t)slot * (128 * 128);
#pragma unroll
    for (int nt = 0; nt < 2; ++nt)
#pragma unroll
      for (int r = 0; r < 4; ++r) {
        const int dv = dv0 + 4 * q4 + r;
        const int dk = 32 * w + 16 * nt + li;
        st[sb + (size_t)dv * 128 + dk] = f2bf(acc[nt][r]);
      }
  };

  for (int j = 0; j < CPS; ++j) {
    __syncthreads();  // prev chunk's frag reads done
    // stage K^T (ushort4 along t) and V^T (ushort2 along t)
#pragma unroll
    for (int p = 0; p < 4; ++p) {
      const int t0 = p * 32 + ktg4;
#pragma unroll
      for (int jj = 0; jj < 4; ++jj) {
        ushort4 u;
        u.x = f2bf(((const float*)&rk[p][0])[jj]);
        u.y = f2bf(((const float*)&rk[p][1])[jj]);
        u.z = f2bf(((const float*)&rk[p][2])[jj]);
        u.w = f2bf(((const float*)&rk[p][3])[jj]);
        *(ushort4*)&KT[swKT(kdk0 + jj, t0)] = u;
      }
    }
#pragma unroll
    for (int jj = 0; jj < 4; ++jj) {
      ushort2 u;
      u.x = f2bf(((const float*)&rv[0])[jj]);
      u.y = f2bf(((const float*)&rv[1])[jj]);
      *(ushort2*)&VT[swVT(vdv0l + jj, vt0)] = u;
    }
    if (j + 1 < CPS) prefetch(n0 + j + 1);  // HBM latency hides under LDS+MFMA
    __syncthreads();
    // store local EXCLUSIVE prefix (slot 4s+j, j>0; j==0 local prefix is 0)
    if (j > 0) store_acc(n0 + j);
    // acc[dv][dk] += V^T K  (wave w owns dk in [32w, 32w+32))
#pragma unroll
    for (int kt = 0; kt < 4; ++kt) {
      frag_ab af = *(const frag_ab*)&VT[swVT(li, 32 * kt + 8 * q4)];
#pragma unroll
      for (int nt = 0; nt < 2; ++nt) {
        frag_ab bf = *(const frag_ab*)&KT[swKT(32 * w + 16 * nt + li, 32 * kt + 8 * q4)];
        acc[nt] = __builtin_amdgcn_mfma_f32_16x16x32_bf16(af, bf, acc[nt], 0, 0, 0);
      }
    }
  }
  // segment total T_seg -> slot n0 (unused by last segment's consumers)
  if (seg + 1 < NSEG) store_acc(n0);
}

// ---------- phB: O = Qs*H_n + tril(Qs*K^T)*V, 64 query rows per block ----
// H_n = sum_{sig < n>>2} T_sig (slots 4*sig) + local (slot n, if n&3).
// bid: bh low 6 bits, n bits 6-9, tb bit 10 -> partners (+1024) and a bh's
// chunks (+64) land on the same XCD under mod-8 round robin (L2 reuse of
// carry totals / shared K,V,H).
__global__ __launch_bounds__(256, 4) void phB_out(const float* __restrict__ qg,
                                                  const float* __restrict__ kg,
                                                  const float* __restrict__ vg,
                                                  const unsigned short* __restrict__ st,
                                                  float* __restrict__ o) {
  __shared__ unsigned short QP[64 * 128];   // 16 KB: Qs rows of this tb, later P
  __shared__ unsigned short Bb[128 * 64];   // 16 KB: H / K / V^T stages
  const int tid = threadIdx.x;
  const int bid = blockIdx.x;
  const int bh = bid & 63, n = (bid >> 6) & 15, tb = bid >> 10;
  const int b = bh >> 4, h = bh & 15;
  const size_t cbase = (size_t)b * Sq * RS + (size_t)n * Cc * RS + (size_t)h * Dd;
  const size_t tbase = cbase + (size_t)(64 * tb) * RS;
  const size_t sbh = (size_t)bh * NCH * (128 * 128);
  const int sseg = n >> 2, jj = n & 3;
  const int nmat = sseg + (jj ? 1 : 0);
  const int w = tid >> 6, L = tid & 63;
  const int wr = w >> 1, wc = w & 1, li = L & 15, q4 = L >> 4;

  // stage Qs (64 rows of this tb, scaled) -> QP
#pragma unroll
  for (int it = 0; it < 8; ++it) {
    const int f = it * 256 + tid;
    const int t = f >> 5;
    const int c0 = (f & 31) << 2;
    const float4 q4v = *(const float4*)(qg + tbase + (size_t)t * RS + c0);
    ushort4 qu;
    qu.x = f2bf(q4v.x * SCALE); qu.y = f2bf(q4v.y * SCALE);
    qu.z = f2bf(q4v.z * SCALE); qu.w = f2bf(q4v.w * SCALE);
    *(ushort4*)&QP[sw128(t, c0)] = qu;
  }
  frag_cd accO[2][4], accP[2][4];
#pragma unroll
  for (int i = 0; i < 2; ++i)
#pragma unroll
    for (int j = 0; j < 4; ++j) {
      accO[i][j] = (frag_cd){0.f, 0.f, 0.f, 0.f};
      accP[i][j] = (frag_cd){0.f, 0.f, 0.f, 0.f};
    }

  // ---- H-GEMM: accO = Qs (from QP) x H  (H = carry totals + local) ----
  if (nmat > 0) {
    for (int half = 0; half < 2; ++half) {
      __syncthreads();  // half0: QP visible; half1: Bb reads done
      if (nmat == 1) {
        const int slot = sseg ? 0 : n;  // sseg==1,jj==0 -> T_0; else local n
#pragma unroll
        for (int it = 0; it < 4; ++it) {
          const int f = it * 256 + tid;
          const int dv = f >> 3;
          const int c8 = (f & 7) << 3;
          const uint4 hv = *(const uint4*)(st + sbh + ((size_t)slot << 14) +
                                           (size_t)dv * 128 + 64 * half + c8);
          *(uint4*)&Bb[sw64(dv, c8)] = hv;
        }
      } else {
#pragma unroll
        for (int it = 0; it < 4; ++it) {
          const int f = it * 256 + tid;
          const int dv = f >> 3;
          const int c8 = (f & 7) << 3;
          float s8[8];
#pragma unroll
          for (int e = 0; e < 8; ++e) s8[e] = 0.f;
          for (int m = 0; m < nmat; ++m) {
            const int slot = (m < sseg) ? (m << 2) : n;
            const uint4 hv = *(const uint4*)(st + sbh + ((size_t)slot << 14) +
                                             (size_t)dv * 128 + 64 * half + c8);
            const unsigned hw[4] = {hv.x, hv.y, hv.z, hv.w};
#pragma unroll
            for (int e = 0; e < 4; ++e) {
              s8[2 * e + 0] += bf2f((unsigned short)(hw[e] & 0xFFFFu));
              s8[2 * e + 1] += bf2f((unsigned short)(hw[e] >> 16));
            }
          }
          unsigned pk[4];
#pragma unroll
          for (int e = 0; e < 4; ++e)
            pk[e] = (unsigned)f2bf(s8[2 * e]) | ((unsigned)f2bf(s8[2 * e + 1]) << 16);
          uint4 hv; hv.x = pk[0]; hv.y = pk[1]; hv.z = pk[2]; hv.w = pk[3];
          *(uint4*)&Bb[sw64(dv, c8)] = hv;
        }
      }
      __syncthreads();
#pragma unroll
      for (int kt = 0; kt < 2; ++kt) {
        const int ktg = 2 * half + kt;
        frag_ab af[2], bf_[4];
#pragma unroll
        for (int mt = 0; mt < 2; ++mt)
          af[mt] = *(const frag_ab*)&QP[sw128(32 * wr + 16 * mt + li, 32 * ktg + 8 * q4)];
#pragma unroll
        for (int nt = 0; nt < 4; ++nt)
          bf_[nt] = *(const frag_ab*)&Bb[sw64(64 * wc + 16 * nt + li, 32 * kt + 8 * q4)];
#pragma unroll
        for (int mt = 0; mt < 2; ++mt)
#pragma unroll
          for (int nt = 0; nt < 4; ++nt)
            accO[mt][nt] = __builtin_amdgcn_mfma_f32_16x16x32_bf16(af[mt], bf_[nt], accO[mt][nt], 0, 0, 0);
      }
    }
  }

  // ---- GEMM1: accP = Qs x K^T (triangle-skipped) ----
  // K rows (= P cols s) needed: tb=0 -> 0..63 only; tb=1 -> all 128.
  for (int half = 0; half < 2; ++half) {
    __syncthreads();
    if (tb) {
#pragma unroll
      for (int it = 0; it < 8; ++it) {
        const int f = it * 256 + tid;
        const int t = f >> 4;
        const int c0 = (f & 15) << 2;
        const float4 k4v = *(const float4*)(kg + cbase + (size_t)t * RS + 64 * half + c0);
        ushort4 ku;
        ku.x = f2bf(k4v.x); ku.y = f2bf(k4v.y); ku.z = f2bf(k4v.z); ku.w = f2bf(k4v.w);
        *(ushort4*)&Bb[sw64(t, c0)] = ku;
      }
    } else {
#pragma unroll
      for (int it = 0; it < 4; ++it) {
        const int f = it * 256 + tid;
        const int t = f >> 4;
        const int c0 = (f & 15) << 2;
        const float4 k4v = *(const float4*)(kg + cbase + (size_t)t * RS + 64 * half + c0);
        ushort4 ku;
        ku.x = f2bf(k4v.x); ku.y = f2bf(k4v.y); ku.z = f2bf(k4v.z); ku.w = f2bf(k4v.w);
        *(ushort4*)&Bb[sw64(t, c0)] = ku;
      }
    }
    __syncthreads();
    if (64 * wc <= 64 * tb + 32 * wr + 31) {
#pragma unroll
      for (int kt = 0; kt < 2; ++kt) {
        const int ktg = 2 * half + kt;
        frag_ab af[2], bf_[4];
#pragma unroll
        for (int mt = 0; mt < 2; ++mt)
          af[mt] = *(const frag_ab*)&QP[sw128(32 * wr + 16 * mt + li, 32 * ktg + 8 * q4)];
#pragma unroll
        for (int nt = 0; nt < 4; ++nt)
          bf_[nt] = *(const frag_ab*)&Bb[sw64(64 * wc + 16 * nt + li, 32 * kt + 8 * q4)];
#pragma unroll
        for (int mt = 0; mt < 2; ++mt)
#pragma unroll
          for (int nt = 0; nt < 4; ++nt)
            if (64 * wc + 16 * nt <= 64 * tb + 32 * wr + 16 * mt + 15)
              accP[mt][nt] = __builtin_amdgcn_mfma_f32_16x16x32_bf16(af[mt], bf_[nt], accP[mt][nt], 0, 0, 0);
      }
    }
  }
  __syncthreads();  // all QP (Qs) reads done -> safe to overwrite with P
  // masked P (s <= global t) -> QP
#pragma unroll
  for (int mt = 0; mt < 2; ++mt)
#pragma unroll
    for (int nt = 0; nt < 4; ++nt) {
      const int t0 = 32 * wr + 16 * mt + 4 * q4;
      const int s = 64 * wc + 16 * nt + li;
#pragma unroll
      for (int r = 0; r < 4; ++r) {
        const int t = t0 + r;
        QP[sw128(t, s)] = (s <= t + 64 * tb) ? f2bf(accP[mt][nt][r]) : (unsigned short)0;
      }
    }

  // ---- GEMM2: accO += P x V  (V^T staged into Bb; tb=0 needs s-half 0 only) ----
  const int nh2 = tb ? 2 : 1;
  for (int half = 0; half < nh2; ++half) {
    __syncthreads();  // P visible / Bb reads done
#pragma unroll
    for (int it = 0; it < 8; ++it) {
      const int sl = (tid & 15) | ((it & 3) << 4);
      const int c0 = ((tid >> 4) | ((it >> 2) << 4)) << 2;
      const int s = 64 * half + sl;
      const float4 v4v = *(const float4*)(vg + cbase + (size_t)s * RS + c0);
      Bb[sw64(c0 + 0, sl)] = f2bf(v4v.x);
      Bb[sw64(c0 + 1, sl)] = f2bf(v4v.y);
      Bb[sw64(c0 + 2, sl)] = f2bf(v4v.z);
      Bb[sw64(c0 + 3, sl)] = f2bf(v4v.w);
    }
    __syncthreads();
#pragma unroll
    for (int kt = 0; kt < 2; ++kt) {
      const int ktg = 2 * half + kt;
      if (32 * ktg > 64 * tb + 32 * wr + 31) continue;
      frag_ab af[2], bf_[4];
#pragma unroll
      for (int mt = 0; mt < 2; ++mt)
        af[mt] = *(const frag_ab*)&QP[sw128(32 * wr + 16 * mt + li, 32 * ktg + 8 * q4)];
#pragma unroll
      for (int nt = 0; nt < 4; ++nt)
        bf_[nt] = *(const frag_ab*)&Bb[sw64(64 * wc + 16 * nt + li, 32 * kt + 8 * q4)];
#pragma unroll
      for (int mt = 0; mt < 2; ++mt)
#pragma unroll
        for (int nt = 0; nt < 4; ++nt)
          if (32 * ktg <= 64 * tb + 32 * wr + 16 * mt + 15)
            accO[mt][nt] = __builtin_amdgcn_mfma_f32_16x16x32_bf16(af[mt], bf_[nt], accO[mt][nt], 0, 0, 0);
    }
  }
  // store O fp32 (single write, no RMW)
#pragma unroll
  for (int mt = 0; mt < 2; ++mt)
#pragma unroll
    for (int nt = 0; nt < 4; ++nt)
#pragma unroll
      for (int r = 0; r < 4; ++r) {
        const int t = 32 * wr + 16 * mt + 4 * q4 + r;
        const int dv = 64 * wc + 16 * nt + li;
        o[tbase + (size_t)t * RS + dv] = accO[mt][nt][r];
      }
}

extern "C" void kernel_launch(void* const* d_in, const int* in_sizes, int n_in,
                              void* d_out, int out_size, void* d_ws, size_t ws_size,
                              hipStream_t stream) {
  const float* q = (const float*)d_in[0];
  const float* k = (const float*)d_in[1];
  const float* v = (const float*)d_in[2];
  float* o = (float*)d_out;
  unsigned short* st = (unsigned short*)d_ws;  // 32 MiB
  hipLaunchKernelGGL(phA_state, dim3(BHt * 8 * NSEG), dim3(256), 0, stream, k, v, st);
  hipLaunchKernelGGL(phB_out, dim3(BHt * NCH * 2), dim3(256), 0, stream, q, k, v, st, o);
}